// Round 2
// baseline (105.455 us; speedup 1.0000x reference)
//
#include <hip/hip_runtime.h>

// Dilated attention, collapsed form.
// q,k,v: [B=4, D=256, N=8192] f32 (n contiguous). out: [B, N, D] f32.
// HEAD_DIM=32, heads H=8, kernel offsets {-2,0,+2}, 6 zero-pad slots in softmax.
//
// R2: register-lean version. No o[32] accumulator (v-pass streams channel
// groups of 4 straight to float4 stores), no dead qreg, 32-bit offsets.
// __launch_bounds__(256,8) forces VGPR<=64 -> 8 waves/SIMD (was 116 VGPR /
// 4 waves -> 15% occupancy, latency-bound).

constexpr int Bn = 4;
constexpr int Dd = 256;
constexpr int Nn = 8192;
constexpr int HD = 32;
constexpr int Hh = Dd / HD;          // 8
constexpr float SCALE = 0.17677669529663687f;  // 32^-0.5

__global__ __launch_bounds__(256, 8) void dilate_attn_kernel(
    const float* __restrict__ q,
    const float* __restrict__ k,
    const float* __restrict__ v,
    float* __restrict__ out)
{
    const int gid = blockIdx.x * blockDim.x + threadIdx.x;   // B*H*N threads
    const int n  = gid & (Nn - 1);          // consecutive lanes -> consecutive n
    const int bh = gid >> 13;               // N = 8192 = 2^13
    const int h  = bh & (Hh - 1);
    const int b  = bh >> 3;

    const int base = (b * Dd + h * HD) * Nn + n;   // fits in int (max 8.4M)
    const float* qb = q + base;
    const float* kb = k + base;
    const float* vb = v + base;

    const bool left  = (n >= 2);
    const bool right = (n < Nn - 2);

    // ---- phase 1: logits (dot over all 32 channels) ----
    float s0 = 0.f, s1 = 0.f, s2 = 0.f;
    #pragma unroll
    for (int c = 0; c < HD; ++c) {
        const float qc = qb[c * Nn];
        const float k1 = kb[c * Nn];
        const float k0 = left  ? kb[c * Nn - 2] : 0.f;
        const float k2 = right ? kb[c * Nn + 2] : 0.f;
        s0 = fmaf(qc, k0, s0);
        s1 = fmaf(qc, k1, s1);
        s2 = fmaf(qc, k2, s2);
    }
    s0 *= SCALE; s1 *= SCALE; s2 *= SCALE;

    // ---- phase 2: softmax over [s0,s1,s2] + six exact-zero pad logits ----
    const float m  = fmaxf(fmaxf(s0, s1), fmaxf(s2, 0.f));
    const float e0 = __expf(s0 - m);
    const float e1 = __expf(s1 - m);
    const float e2 = __expf(s2 - m);
    const float ez = __expf(-m);
    const float inv = 1.f / (e0 + e1 + e2 + 6.f * ez);
    const float p0 = e0 * inv, p1 = e1 * inv, p2 = e2 * inv;

    // ---- phase 3: PV, streamed in channel groups of 4 (no o[32] array) ----
    // out[b][n][h*32 + c], c contiguous: 8x float4 per thread
    float* ob = out + (b * Nn + n) * Dd + h * HD;
    #pragma unroll
    for (int cg = 0; cg < HD; cg += 4) {
        float4 t;
        float* tp = &t.x;
        #pragma unroll
        for (int j = 0; j < 4; ++j) {
            const int c = cg + j;
            const float v1 = vb[c * Nn];
            const float v0 = left  ? vb[c * Nn - 2] : 0.f;
            const float v2 = right ? vb[c * Nn + 2] : 0.f;
            tp[j] = fmaf(p0, v0, fmaf(p1, v1, p2 * v2));
        }
        *reinterpret_cast<float4*>(ob + cg) = t;
    }
}

extern "C" void kernel_launch(void* const* d_in, const int* in_sizes, int n_in,
                              void* d_out, int out_size, void* d_ws, size_t ws_size,
                              hipStream_t stream)
{
    const float* q = (const float*)d_in[0];
    const float* k = (const float*)d_in[1];
    const float* v = (const float*)d_in[2];
    float* out = (float*)d_out;

    const int total = Bn * Hh * Nn;          // 262144 threads
    dilate_attn_kernel<<<total / 256, 256, 0, stream>>>(q, k, v, out);
}

// Round 3
// 40.293 us; speedup vs baseline: 2.6172x; 2.6172x over previous
//
#include <hip/hip_runtime.h>

// Dilated attention, collapsed form.
// q,k,v: [B=4, D=256, N=8192] f32 (n contiguous). out: [B, N, D] f32.
// HEAD_DIM=32, heads H=8, offsets {-2,0,+2} along n, 6 zero-pad softmax slots.
//
// R3: addressing fix. (b,h) derived from blockIdx only -> channel base is
// wave-uniform (SGPR); per-lane address is one VGPR (n*4); the +/-2 taps fold
// into load immediates. 2 n per thread -> float2 loads (8 B/lane). No
// min-wave forcing (R2's forced 32 VGPR spilled: WRITE 33->179 MB, 105 us).

constexpr int Bn = 4;
constexpr int Dd = 256;
constexpr int Nn = 8192;
constexpr int HD = 32;
constexpr int Hh = Dd / HD;          // 8
constexpr float SCALE = 0.17677669529663687f;  // 32^-0.5

__global__ __launch_bounds__(256) void dilate_attn_kernel(
    const float* __restrict__ q,
    const float* __restrict__ k,
    const float* __restrict__ v,
    float* __restrict__ out)
{
    // 16 blocks per (b,h); each block covers 512 n (256 threads x 2 n).
    const int blk = blockIdx.x;
    const int bh  = blk >> 4;                      // provably uniform
    const int h   = bh & (Hh - 1);
    const int b   = bh >> 3;
    const int n   = ((blk & 15) << 9) | (threadIdx.x << 1);   // even, 0..8190

    const int cb = (b * Dd + h * HD) * Nn;         // uniform channel base
    const float* qb = q + cb + n;
    const float* kb = k + cb + n;
    const float* vb = v + cb + n;

    const bool left  = (n >= 2);
    const bool right = (n < Nn - 2);

    // ---- phase 1: logits for positions n (x) and n+1 (y) ----
    float s0x = 0.f, s0y = 0.f, s1x = 0.f, s1y = 0.f, s2x = 0.f, s2y = 0.f;
    #pragma unroll
    for (int c = 0; c < HD; ++c) {
        const int o = c * Nn;                      // uniform -> SGPR base step
        const float2 qc = *reinterpret_cast<const float2*>(qb + o);
        const float2 kc = *reinterpret_cast<const float2*>(kb + o);
        float2 km = make_float2(0.f, 0.f), kp = make_float2(0.f, 0.f);
        if (left)  km = *reinterpret_cast<const float2*>(kb + o - 2);
        if (right) kp = *reinterpret_cast<const float2*>(kb + o + 2);
        // pos n:   k[n-2]=km.x  k[n]=kc.x  k[n+2]=kp.x
        // pos n+1: k[n-1]=km.y  k[n+1]=kc.y  k[n+3]=kp.y
        s0x = fmaf(qc.x, km.x, s0x);
        s1x = fmaf(qc.x, kc.x, s1x);
        s2x = fmaf(qc.x, kp.x, s2x);
        s0y = fmaf(qc.y, km.y, s0y);
        s1y = fmaf(qc.y, kc.y, s1y);
        s2y = fmaf(qc.y, kp.y, s2y);
    }
    s0x *= SCALE; s1x *= SCALE; s2x *= SCALE;
    s0y *= SCALE; s1y *= SCALE; s2y *= SCALE;

    // ---- phase 2: softmax over 3 real logits + six exact-zero pad logits ----
    const float mx  = fmaxf(fmaxf(s0x, s1x), fmaxf(s2x, 0.f));
    const float e0x = __expf(s0x - mx), e1x = __expf(s1x - mx), e2x = __expf(s2x - mx);
    const float ivx = 1.f / (e0x + e1x + e2x + 6.f * __expf(-mx));
    const float p0x = e0x * ivx, p1x = e1x * ivx, p2x = e2x * ivx;

    const float my  = fmaxf(fmaxf(s0y, s1y), fmaxf(s2y, 0.f));
    const float e0y = __expf(s0y - my), e1y = __expf(s1y - my), e2y = __expf(s2y - my);
    const float ivy = 1.f / (e0y + e1y + e2y + 6.f * __expf(-my));
    const float p0y = e0y * ivy, p1y = e1y * ivy, p2y = e2y * ivy;

    // ---- phase 3: PV streamed in channel groups of 4, float4 stores ----
    float* obx = out + (b * Nn + n) * Dd + h * HD;   // row n
    float* oby = obx + Dd;                           // row n+1
    #pragma unroll
    for (int cg = 0; cg < HD; cg += 4) {
        float4 tx, ty;
        float* tpx = &tx.x;
        float* tpy = &ty.x;
        #pragma unroll
        for (int j = 0; j < 4; ++j) {
            const int o = (cg + j) * Nn;
            const float2 vc = *reinterpret_cast<const float2*>(vb + o);
            float2 vm = make_float2(0.f, 0.f), vp = make_float2(0.f, 0.f);
            if (left)  vm = *reinterpret_cast<const float2*>(vb + o - 2);
            if (right) vp = *reinterpret_cast<const float2*>(vb + o + 2);
            tpx[j] = fmaf(p0x, vm.x, fmaf(p1x, vc.x, p2x * vp.x));
            tpy[j] = fmaf(p0y, vm.y, fmaf(p1y, vc.y, p2y * vp.y));
        }
        *reinterpret_cast<float4*>(obx + cg) = tx;
        *reinterpret_cast<float4*>(oby + cg) = ty;
    }
}

extern "C" void kernel_launch(void* const* d_in, const int* in_sizes, int n_in,
                              void* d_out, int out_size, void* d_ws, size_t ws_size,
                              hipStream_t stream)
{
    const float* q = (const float*)d_in[0];
    const float* k = (const float*)d_in[1];
    const float* v = (const float*)d_in[2];
    float* out = (float*)d_out;

    const int total_threads = Bn * Hh * Nn / 2;    // 131072
    dilate_attn_kernel<<<total_threads / 256, 256, 0, stream>>>(q, k, v, out);
}

// Round 4
// 34.209 us; speedup vs baseline: 3.0827x; 1.1779x over previous
//
#include <hip/hip_runtime.h>

// Dilated attention, collapsed form.
// q,k,v: [B=4, D=256, N=8192] f32 (n contiguous). out: [B, N, D] f32.
// HEAD_DIM=32, heads H=8, taps {-2,0,+2} along n, 6 zero-pad softmax slots.
//
// R4: channel-split. Each thread owns 8 of the 32 head channels for one
// (b,h,n): wave = 16 consecutive n x 4 channel-quarters. Partial logits
// reduced via __shfl_xor(16|32). Per-thread loads 224 -> 56, small live set
// -> low VGPR; grid 4096 blocks -> residency no longer grid- or VGPR-capped.
// (R1: 116 VGPR/15% occ; R2 forced 8 waves -> spills; R3: 144 VGPR/9% occ.)

constexpr int Bn = 4;
constexpr int Dd = 256;
constexpr int Nn = 8192;
constexpr int HD = 32;
constexpr int Hh = Dd / HD;          // 8
constexpr float SCALE = 0.17677669529663687f;  // 32^-0.5

__global__ __launch_bounds__(256) void dilate_attn_kernel(
    const float* __restrict__ q,
    const float* __restrict__ k,
    const float* __restrict__ v,
    float* __restrict__ out)
{
    const int tid     = threadIdx.x;
    const int lane    = tid & 63;
    const int sub     = lane & 15;        // n offset within wave
    const int quarter = lane >> 4;        // which 8 channels (0..3)
    const int w       = tid >> 6;         // wave in block (0..3)

    const int blk = blockIdx.x;           // 4096 blocks
    const int bh  = blk >> 7;             // 128 blocks per (b,h)
    const int h   = bh & (Hh - 1);
    const int b   = bh >> 3;
    const int n   = ((blk & 127) << 6) + (w << 4) + sub;   // block covers 64 n

    const int cb = (b * Dd + h * HD + quarter * 8) * Nn + n;  // fits in int
    const float* qb = q + cb;
    const float* kb = k + cb;
    const float* vb = v + cb;

    const bool left  = (n >= 2);
    const bool right = (n < Nn - 2);

    // ---- phase 1: partial logits over this thread's 8 channels ----
    float s0 = 0.f, s1 = 0.f, s2 = 0.f;
    #pragma unroll
    for (int c = 0; c < 8; ++c) {
        const int o = c * Nn;             // uniform -> SGPR base step
        const float qc = qb[o];
        const float k1 = kb[o];
        const float k0 = left  ? kb[o - 2] : 0.f;
        const float k2 = right ? kb[o + 2] : 0.f;
        s0 = fmaf(qc, k0, s0);
        s1 = fmaf(qc, k1, s1);
        s2 = fmaf(qc, k2, s2);
    }
    // reduce across the 4 channel-quarters (lanes l, l^16, l^32, l^48)
    s0 += __shfl_xor(s0, 16, 64);  s0 += __shfl_xor(s0, 32, 64);
    s1 += __shfl_xor(s1, 16, 64);  s1 += __shfl_xor(s1, 32, 64);
    s2 += __shfl_xor(s2, 16, 64);  s2 += __shfl_xor(s2, 32, 64);
    s0 *= SCALE; s1 *= SCALE; s2 *= SCALE;

    // ---- phase 2: softmax over 3 real logits + six exact-zero pad logits ----
    const float m  = fmaxf(fmaxf(s0, s1), fmaxf(s2, 0.f));
    const float e0 = __expf(s0 - m);
    const float e1 = __expf(s1 - m);
    const float e2 = __expf(s2 - m);
    const float inv = 1.f / (e0 + e1 + e2 + 6.f * __expf(-m));
    const float p0 = e0 * inv, p1 = e1 * inv, p2 = e2 * inv;

    // ---- phase 3: PV over this thread's 8 channels, two float4 stores ----
    float4 t0, t1;
    float* tp0 = &t0.x;
    float* tp1 = &t1.x;
    #pragma unroll
    for (int c = 0; c < 8; ++c) {
        const int o = c * Nn;
        const float v1 = vb[o];
        const float v0 = left  ? vb[o - 2] : 0.f;
        const float v2 = right ? vb[o + 2] : 0.f;
        const float oc = fmaf(p0, v0, fmaf(p1, v1, p2 * v2));
        if (c < 4) tp0[c] = oc; else tp1[c - 4] = oc;
    }
    // out[b][n][h*32 + quarter*8 + j]: 32 B contiguous per lane; the wave's
    // 4 quarters tile complete 128-B rows.
    float* ob = out + (b * Nn + n) * Dd + h * HD + quarter * 8;
    *reinterpret_cast<float4*>(ob)     = t0;
    *reinterpret_cast<float4*>(ob + 4) = t1;
}

extern "C" void kernel_launch(void* const* d_in, const int* in_sizes, int n_in,
                              void* d_out, int out_size, void* d_ws, size_t ws_size,
                              hipStream_t stream)
{
    const float* q = (const float*)d_in[0];
    const float* k = (const float*)d_in[1];
    const float* v = (const float*)d_in[2];
    float* out = (float*)d_out;

    const int total_threads = Bn * Hh * Nn * 4;    // 1,048,576 (4 lanes per pos)
    dilate_attn_kernel<<<total_threads / 256, 256, 0, stream>>>(q, k, v, out);
}

// Round 5
// 33.441 us; speedup vs baseline: 3.1535x; 1.0230x over previous
//
#include <hip/hip_runtime.h>

// Dilated attention, collapsed form.
// q,k,v: [B=4, D=256, N=8192] f32 (n contiguous). out: [B, N, D] f32.
// HEAD_DIM=32, heads H=8, taps {-2,0,+2} along n, 6 zero-pad softmax slots.
//
// R5: quad-of-n + channel-quarter split. Thread = (b,h, 4 consecutive n,
// octet of channels). All loads are float4 (center quad) + float2 (exact
// 8 B halos at n0-2 / n0+4): per-channel k/v = 32 B in 3 instrs, zero waste.
// Wave-load-instrs 950K -> 262K vs R4; channel-split keeps registers low.
// Logit partials reduced with __shfl_xor(16|32).
// History: R1 116VGPR/15%occ 43us; R2 forced->spill 105us; R3 144VGPR 59us;
// R4 scalar loads, 20VGPR/58%occ, 41us cold (VMEM-instr/latency-bound).

constexpr int Bn = 4;
constexpr int Dd = 256;
constexpr int Nn = 8192;
constexpr int HD = 32;
constexpr int Hh = Dd / HD;          // 8
constexpr float SCALE = 0.17677669529663687f;  // 32^-0.5

__global__ __launch_bounds__(256) void dilate_attn_kernel(
    const float* __restrict__ q,
    const float* __restrict__ k,
    const float* __restrict__ v,
    float* __restrict__ out)
{
    const int tid     = threadIdx.x;
    const int lane    = tid & 63;
    const int sub     = lane & 15;        // n-quad index within wave
    const int quarter = lane >> 4;        // channel octet (0..3)
    const int w       = tid >> 6;         // wave in block (0..3)

    const int blk = blockIdx.x;           // 1024 blocks
    const int bh  = blk >> 5;             // 32 blocks per (b,h)
    const int h   = bh & (Hh - 1);
    const int b   = bh >> 3;
    // block covers 256 n: 4 waves x 16 quads x 4 n
    const int n0  = ((blk & 31) << 8) + (w << 6) + (sub << 2);

    const int cb = (b * Dd + h * HD + quarter * 8) * Nn + n0;  // fits in int
    const float* qb = q + cb;
    const float* kb = k + cb;
    const float* vb = v + cb;

    const bool hasL = (n0 >= 4);          // float2 at n0-2 fully in-bounds
    const bool hasR = (n0 + 4 < Nn);      // float2 at n0+4 fully in-bounds

    // ---- phase 1: partial logits for rows n0..n0+3 over 8 channels ----
    // taps per row j (k[n0+j-2], k[n0+j], k[n0+j+2]):
    //  j=0: km.x kc.x kc.z | j=1: km.y kc.y kc.w
    //  j=2: kc.x kc.z kp.x | j=3: kc.y kc.w kp.y
    float s0[4] = {0.f, 0.f, 0.f, 0.f};
    float s1[4] = {0.f, 0.f, 0.f, 0.f};
    float s2[4] = {0.f, 0.f, 0.f, 0.f};
    #pragma unroll
    for (int c = 0; c < 8; ++c) {
        const int o = c * Nn;             // uniform -> SGPR base step
        const float4 qc = *reinterpret_cast<const float4*>(qb + o);
        const float4 kc = *reinterpret_cast<const float4*>(kb + o);
        float2 km = make_float2(0.f, 0.f), kp = make_float2(0.f, 0.f);
        if (hasL) km = *reinterpret_cast<const float2*>(kb + o - 2);
        if (hasR) kp = *reinterpret_cast<const float2*>(kb + o + 4);
        s0[0] = fmaf(qc.x, km.x, s0[0]);
        s1[0] = fmaf(qc.x, kc.x, s1[0]);
        s2[0] = fmaf(qc.x, kc.z, s2[0]);
        s0[1] = fmaf(qc.y, km.y, s0[1]);
        s1[1] = fmaf(qc.y, kc.y, s1[1]);
        s2[1] = fmaf(qc.y, kc.w, s2[1]);
        s0[2] = fmaf(qc.z, kc.x, s0[2]);
        s1[2] = fmaf(qc.z, kc.z, s1[2]);
        s2[2] = fmaf(qc.z, kp.x, s2[2]);
        s0[3] = fmaf(qc.w, kc.y, s0[3]);
        s1[3] = fmaf(qc.w, kc.w, s1[3]);
        s2[3] = fmaf(qc.w, kp.y, s2[3]);
    }

    // reduce across the 4 channel-quarters; then softmax per row
    float p0[4], p1[4], p2[4];
    #pragma unroll
    for (int j = 0; j < 4; ++j) {
        float a = s0[j], bb = s1[j], cc = s2[j];
        a  += __shfl_xor(a, 16, 64);  a  += __shfl_xor(a, 32, 64);
        bb += __shfl_xor(bb, 16, 64); bb += __shfl_xor(bb, 32, 64);
        cc += __shfl_xor(cc, 16, 64); cc += __shfl_xor(cc, 32, 64);
        a *= SCALE; bb *= SCALE; cc *= SCALE;
        const float m  = fmaxf(fmaxf(a, bb), fmaxf(cc, 0.f));
        const float e0 = __expf(a - m);
        const float e1 = __expf(bb - m);
        const float e2 = __expf(cc - m);
        const float inv = 1.f / (e0 + e1 + e2 + 6.f * __expf(-m));
        p0[j] = e0 * inv; p1[j] = e1 * inv; p2[j] = e2 * inv;
    }

    // ---- phase 3: PV, channel groups of 4, float4 store per row ----
    #pragma unroll
    for (int cg = 0; cg < 8; cg += 4) {
        float t[4][4];                    // [row j][channel-in-group jc]
        #pragma unroll
        for (int jc = 0; jc < 4; ++jc) {
            const int o = (cg + jc) * Nn;
            const float4 vc = *reinterpret_cast<const float4*>(vb + o);
            float2 vm = make_float2(0.f, 0.f), vp = make_float2(0.f, 0.f);
            if (hasL) vm = *reinterpret_cast<const float2*>(vb + o - 2);
            if (hasR) vp = *reinterpret_cast<const float2*>(vb + o + 4);
            t[0][jc] = fmaf(p0[0], vm.x, fmaf(p1[0], vc.x, p2[0] * vc.z));
            t[1][jc] = fmaf(p0[1], vm.y, fmaf(p1[1], vc.y, p2[1] * vc.w));
            t[2][jc] = fmaf(p0[2], vc.x, fmaf(p1[2], vc.z, p2[2] * vp.x));
            t[3][jc] = fmaf(p0[3], vc.y, fmaf(p1[3], vc.w, p2[3] * vp.y));
        }
        // out[b][n0+j][h*32 + quarter*8 + cg .. +3]
        float* ob = out + (b * Nn + n0) * Dd + h * HD + quarter * 8 + cg;
        #pragma unroll
        for (int j = 0; j < 4; ++j) {
            *reinterpret_cast<float4*>(ob + j * Dd) =
                make_float4(t[j][0], t[j][1], t[j][2], t[j][3]);
        }
    }
}

extern "C" void kernel_launch(void* const* d_in, const int* in_sizes, int n_in,
                              void* d_out, int out_size, void* d_ws, size_t ws_size,
                              hipStream_t stream)
{
    const float* q = (const float*)d_in[0];
    const float* k = (const float*)d_in[1];
    const float* v = (const float*)d_in[2];
    float* out = (float*)d_out;

    // B*H*(N/4) quads x 4 channel-quarters = 262144 threads
    const int total_threads = Bn * Hh * (Nn / 4) * 4;
    dilate_attn_kernel<<<total_threads / 256, 256, 0, stream>>>(q, k, v, out);
}

// Round 7
// 29.307 us; speedup vs baseline: 3.5983x; 1.1411x over previous
//
#include <hip/hip_runtime.h>

// Dilated attention, collapsed form.
// q,k,v: [B=4, D=256, N=8192] f32 (n contiguous). out: [B, N, D] f32.
// HEAD_DIM=32, heads H=8, taps {-2,0,+2} along n, 6 zero-pad softmax slots.
//
// R7 == R6 with the nontemporal-store type fixed (clang ext_vector_type
// instead of HIP_vector_type).
// R6 rationale: R5 wrote each 32B output region as two 16B stores separated
// by a full channel-group pass -> partial-line eviction -> WRITE_SIZE 54 MB
// (output is 32 MB). Now PV accumulates t[4][8] over all 8 channels, then
// each lane stores its row's 32 B as two adjacent back-to-back nontemporal
// stores; a wave's 4 channel-quarters tile complete 128 B row chunks.
// History: R1 43us; R2 spill 105us; R3 59us; R4 41us (scalar, 58% occ);
// R5 41us cold (WRITE inflated 54MB); R6 compile fail.

constexpr int Bn = 4;
constexpr int Dd = 256;
constexpr int Nn = 8192;
constexpr int HD = 32;
constexpr int Hh = Dd / HD;          // 8
constexpr float SCALE = 0.17677669529663687f;  // 32^-0.5

typedef float vfloat4 __attribute__((ext_vector_type(4)));

__global__ __launch_bounds__(256) void dilate_attn_kernel(
    const float* __restrict__ q,
    const float* __restrict__ k,
    const float* __restrict__ v,
    float* __restrict__ out)
{
    const int tid     = threadIdx.x;
    const int lane    = tid & 63;
    const int sub     = lane & 15;        // n-quad index within wave
    const int quarter = lane >> 4;        // channel octet (0..3)
    const int w       = tid >> 6;         // wave in block (0..3)

    const int blk = blockIdx.x;           // 1024 blocks
    const int bh  = blk >> 5;             // 32 blocks per (b,h)
    const int h   = bh & (Hh - 1);
    const int b   = bh >> 3;
    // block covers 256 n: 4 waves x 16 quads x 4 n
    const int n0  = ((blk & 31) << 8) + (w << 6) + (sub << 2);

    const int cb = (b * Dd + h * HD + quarter * 8) * Nn + n0;  // fits in int
    const float* qb = q + cb;
    const float* kb = k + cb;
    const float* vb = v + cb;

    const bool hasL = (n0 >= 4);          // float2 at n0-2 fully in-bounds
    const bool hasR = (n0 + 4 < Nn);      // float2 at n0+4 fully in-bounds

    // ---- phase 1: partial logits for rows n0..n0+3 over 8 channels ----
    // taps per row j (k[n0+j-2], k[n0+j], k[n0+j+2]):
    //  j=0: km.x kc.x kc.z | j=1: km.y kc.y kc.w
    //  j=2: kc.x kc.z kp.x | j=3: kc.y kc.w kp.y
    float s0[4] = {0.f, 0.f, 0.f, 0.f};
    float s1[4] = {0.f, 0.f, 0.f, 0.f};
    float s2[4] = {0.f, 0.f, 0.f, 0.f};
    #pragma unroll
    for (int c = 0; c < 8; ++c) {
        const int o = c * Nn;             // uniform -> SGPR base step
        const float4 qc = *reinterpret_cast<const float4*>(qb + o);
        const float4 kc = *reinterpret_cast<const float4*>(kb + o);
        float2 km = make_float2(0.f, 0.f), kp = make_float2(0.f, 0.f);
        if (hasL) km = *reinterpret_cast<const float2*>(kb + o - 2);
        if (hasR) kp = *reinterpret_cast<const float2*>(kb + o + 4);
        s0[0] = fmaf(qc.x, km.x, s0[0]);
        s1[0] = fmaf(qc.x, kc.x, s1[0]);
        s2[0] = fmaf(qc.x, kc.z, s2[0]);
        s0[1] = fmaf(qc.y, km.y, s0[1]);
        s1[1] = fmaf(qc.y, kc.y, s1[1]);
        s2[1] = fmaf(qc.y, kc.w, s2[1]);
        s0[2] = fmaf(qc.z, kc.x, s0[2]);
        s1[2] = fmaf(qc.z, kc.z, s1[2]);
        s2[2] = fmaf(qc.z, kp.x, s2[2]);
        s0[3] = fmaf(qc.w, kc.y, s0[3]);
        s1[3] = fmaf(qc.w, kc.w, s1[3]);
        s2[3] = fmaf(qc.w, kp.y, s2[3]);
    }

    // reduce across the 4 channel-quarters; then softmax per row
    float p0[4], p1[4], p2[4];
    #pragma unroll
    for (int j = 0; j < 4; ++j) {
        float a = s0[j], bb = s1[j], cc = s2[j];
        a  += __shfl_xor(a, 16, 64);  a  += __shfl_xor(a, 32, 64);
        bb += __shfl_xor(bb, 16, 64); bb += __shfl_xor(bb, 32, 64);
        cc += __shfl_xor(cc, 16, 64); cc += __shfl_xor(cc, 32, 64);
        a *= SCALE; bb *= SCALE; cc *= SCALE;
        const float m  = fmaxf(fmaxf(a, bb), fmaxf(cc, 0.f));
        const float e0 = __expf(a - m);
        const float e1 = __expf(bb - m);
        const float e2 = __expf(cc - m);
        const float inv = 1.f / (e0 + e1 + e2 + 6.f * __expf(-m));
        p0[j] = e0 * inv; p1[j] = e1 * inv; p2[j] = e2 * inv;
    }

    // ---- phase 3: PV over all 8 channels, THEN one 32 B store per row ----
    float t[4][8];                        // [row j][channel c]
    #pragma unroll
    for (int c = 0; c < 8; ++c) {
        const int o = c * Nn;
        const float4 vc = *reinterpret_cast<const float4*>(vb + o);
        float2 vm = make_float2(0.f, 0.f), vp = make_float2(0.f, 0.f);
        if (hasL) vm = *reinterpret_cast<const float2*>(vb + o - 2);
        if (hasR) vp = *reinterpret_cast<const float2*>(vb + o + 4);
        t[0][c] = fmaf(p0[0], vm.x, fmaf(p1[0], vc.x, p2[0] * vc.z));
        t[1][c] = fmaf(p0[1], vm.y, fmaf(p1[1], vc.y, p2[1] * vc.w));
        t[2][c] = fmaf(p0[2], vc.x, fmaf(p1[2], vc.z, p2[2] * vp.x));
        t[3][c] = fmaf(p0[3], vc.y, fmaf(p1[3], vc.w, p2[3] * vp.y));
    }

    // out[b][n0+j][h*32 + quarter*8 .. +7]: 32 B per lane per row, written
    // back-to-back; quarters 0..3 complete each 128 B row chunk. Nontemporal:
    // output is write-once, keep it out of L2.
    float* ob = out + (b * Nn + n0) * Dd + h * HD + quarter * 8;
    #pragma unroll
    for (int j = 0; j < 4; ++j) {
        vfloat4* p = reinterpret_cast<vfloat4*>(ob + j * Dd);
        vfloat4 a = {t[j][0], t[j][1], t[j][2], t[j][3]};
        vfloat4 bq = {t[j][4], t[j][5], t[j][6], t[j][7]};
        __builtin_nontemporal_store(a, p);
        __builtin_nontemporal_store(bq, p + 1);
    }
}

extern "C" void kernel_launch(void* const* d_in, const int* in_sizes, int n_in,
                              void* d_out, int out_size, void* d_ws, size_t ws_size,
                              hipStream_t stream)
{
    const float* q = (const float*)d_in[0];
    const float* k = (const float*)d_in[1];
    const float* v = (const float*)d_in[2];
    float* out = (float*)d_out;

    // B*H*(N/4) quads x 4 channel-quarters = 262144 threads
    const int total_threads = Bn * Hh * (Nn / 4) * 4;
    dilate_attn_kernel<<<total_threads / 256, 256, 0, stream>>>(q, k, v, out);
}